// Round 11
// baseline (129.977 us; speedup 1.0000x reference)
//
#include <hip/hip_runtime.h>
#include <cstdint>

#define B_ 16
#define S_ 1024
#define D_ 512
#define TILE 128
#define BK 32
#define PITCH 36   // legacy-path LDS pitch

typedef float f32x4 __attribute__((ext_vector_type(4)));
typedef short s16x8 __attribute__((ext_vector_type(8)));
typedef unsigned short u16;
typedef unsigned int u32;

__device__ __forceinline__ u16 f2bf(float f) {
    u32 u = __builtin_bit_cast(u32, f);
    u += 0x7FFFu + ((u >> 16) & 1u);
    return (u16)(u >> 16);
}
__device__ __forceinline__ float bf2f(u16 h) {
    return __builtin_bit_cast(float, (u32)h << 16);
}

#define GLD16(g, l) __builtin_amdgcn_global_load_lds( \
    (const __attribute__((address_space(1))) u32*)(g), \
    (__attribute__((address_space(3))) u32*)(l), 16, 0, 0)

// per-batch compact causal P_t elems: sum_qt (qt+1)*128*128 = 589824
#define PT_BATCH 589824
__device__ __forceinline__ int tri128(int qt) { return ((qt * (qt + 1)) >> 1) * 16384; }

// ===== prep: cvt(Q) + cvt(K) + transpose-cvt(V) (round-8 proven) =====
#define TP 66
__global__ __launch_bounds__(256) void prep_kernel(const float* __restrict__ q,
                                                   const float* __restrict__ k,
                                                   const float* __restrict__ v,
                                                   u16* __restrict__ Qb,
                                                   u16* __restrict__ Kb,
                                                   u16* __restrict__ Vt) {
    __shared__ u16 t[64 * TP];
    const int bid = blockIdx.x;
    const int tid = threadIdx.x;
    if (bid < 8192) {
        const float* src = (bid < 4096) ? q : k;
        u16* dst = (bid < 4096) ? Qb : Kb;
        int i = (((bid & 4095) * 256) + tid) * 8;
        float4 a = *(const float4*)(src + i);
        float4 b2 = *(const float4*)(src + i + 4);
        union { ushort4 h[2]; s16x8 v; } r;
        r.h[0] = make_ushort4(f2bf(a.x), f2bf(a.y), f2bf(a.z), f2bf(a.w));
        r.h[1] = make_ushort4(f2bf(b2.x), f2bf(b2.y), f2bf(b2.z), f2bf(b2.w));
        *(s16x8*)(dst + i) = r.v;
    } else {
        int tt = bid - 8192;
        const int d0 = (tt & 7) * 64, j0 = ((tt >> 3) & 15) * 64, b = tt >> 7;
        const int tj = tid >> 2;
        const int td = (tid & 3) * 16;
        const float* src = v + ((size_t)b * S_ + j0 + tj) * D_ + d0 + td;
#pragma unroll
        for (int e = 0; e < 4; ++e) {
            float4 a = *(const float4*)(src + e * 4);
            *(ushort4*)(t + tj * TP + td + e * 4) =
                make_ushort4(f2bf(a.x), f2bf(a.y), f2bf(a.z), f2bf(a.w));
        }
        __syncthreads();
        const int dd = tid >> 2;
        const int jj = (tid & 3) * 16;
        u16* dstp = Vt + ((size_t)b * D_ + d0 + dd) * S_ + j0 + jj;
        u16 tmp[16];
#pragma unroll
        for (int e = 0; e < 16; ++e) tmp[e] = t[(jj + e) * TP + dd];
        *(s16x8*)dstp = *(s16x8*)tmp;
        *(s16x8*)(dstp + 8) = *(s16x8*)(tmp + 8);
    }
}

// swizzled LDS read: logical [row][col(64 bf16)] stored with byte ^= (row&7)<<4
__device__ __forceinline__ s16x8 frag_swz(const u16* lds, int row, int colbyte) {
    int off = row * 128 + (colbyte ^ ((row & 7) << 4));
    return *(const s16x8*)((const char*)lds + off);
}

// m97-style bf16 GEMM tile body (proven): 128x128, BK=64, global_load_lds + swizzle
__device__ __forceinline__ void gemm_body(const u16* ag, const u16* bg, int lda, int ldb,
                                          int nk, u16* lA, u16* lB, f32x4 acc[4][4],
                                          int tid) {
    const int lane = tid & 63, wid = tid >> 6;
    const int l8 = lane >> 3, l7 = lane & 7;
    const int cswz = (l7 ^ l8) * 8;
    const u16* ga[4];
    const u16* gb[4];
#pragma unroll
    for (int q2 = 0; q2 < 4; ++q2) {
        int seg = wid * 4 + q2;
        int row = seg * 8 + l8;
        ga[q2] = ag + (size_t)row * lda + cswz;
        gb[q2] = bg + (size_t)row * ldb + cswz;
    }
    const int wr = (wid >> 1) * 64, wc = (wid & 1) * 64;
    const int r15 = lane & 15;
    const int cb = (lane >> 4) * 16;

    for (int kk = 0; kk < nk; kk += 64) {
#pragma unroll
        for (int q2 = 0; q2 < 4; ++q2) {
            int seg = wid * 4 + q2;
            GLD16(ga[q2] + kk, lA + seg * 512);
            GLD16(gb[q2] + kk, lB + seg * 512);
        }
        __syncthreads();
#pragma unroll
        for (int ks = 0; ks < 2; ++ks) {
            s16x8 af[4], bf4[4];
#pragma unroll
            for (int m = 0; m < 4; ++m) af[m] = frag_swz(lA, wr + m * 16 + r15, ks * 64 + cb);
#pragma unroll
            for (int n = 0; n < 4; ++n) bf4[n] = frag_swz(lB, wc + n * 16 + r15, ks * 64 + cb);
#pragma unroll
            for (int m = 0; m < 4; ++m)
#pragma unroll
                for (int n = 0; n < 4; ++n)
                    acc[m][n] = __builtin_amdgcn_mfma_f32_16x16x32_bf16(af[m], bf4[n], acc[m][n], 0, 0, 0);
        }
        __syncthreads();
    }
}

// ===== qk4: proven gemm_body (GLD16 A+B) + round-10 exp epilogue -> Pt bf16 + st =====
__global__ __launch_bounds__(256) void qk4_kernel(const u16* __restrict__ Qb,
                                                  const u16* __restrict__ Kb,
                                                  const int* __restrict__ rep,
                                                  u16* __restrict__ Pt,
                                                  float2* __restrict__ st) {
    const int bid = blockIdx.x;
    const int xcd = bid & 7;
    const int w = bid >> 3;            // 0..71
    const int b = xcd * 2 + (w & 1);
    int p = 35 - (w >> 1);             // LPT
    int qt = 0, tri = 0;
    while (p >= tri + qt + 1) { tri += qt + 1; ++qt; }
    const int kt = p - tri;
    const int nkq = (qt + 1) * 128;

    __shared__ u16 lA[128 * 64];
    __shared__ u16 lB[128 * 64];
    __shared__ int lrepr[128];
    __shared__ int lrepc[128];
    __shared__ float lst[2][64][2][2];   // [row half][row64][col half][max/sum]

    const int tid = threadIdx.x, lane = tid & 63, wid = tid >> 6;
    const int r15 = lane & 15, g4 = lane >> 4;
    if (tid < 128) lrepr[tid] = rep[(size_t)b * S_ + qt * 128 + tid];
    else lrepc[tid - 128] = rep[(size_t)b * S_ + kt * 128 + (tid - 128)];

    f32x4 acc[4][4] = {};
    gemm_body(Qb + ((size_t)b * S_ + (size_t)qt * 128) * D_,
              Kb + ((size_t)b * S_ + (size_t)kt * 128) * D_,
              D_, D_, D_, lA, lB, acc, tid);

    const float scale = 0.04419417382415922f;  // 1/sqrt(512)
    const int wr = (wid >> 1) * 64, wc = (wid & 1) * 64;

    // pass 1: FULL-tile row max (both column halves)
#pragma unroll
    for (int m = 0; m < 4; ++m)
#pragma unroll
        for (int r = 0; r < 4; ++r) {
            const int rowl = m * 16 + g4 * 4 + r;
            const int row = wr + rowl;
            const int gi = qt * 128 + row;
            const int im = lrepr[row];
            float mx = 0.0f;   // masked entries contribute 0 to the max (reference)
#pragma unroll
            for (int n = 0; n < 4; ++n) {
                const int col = wc + n * 16 + r15;
                const int gj = kt * 128 + col;
                if (im && (gj < gi) && (lrepc[col] != 0))
                    mx = fmaxf(mx, acc[m][n][r] * scale - (float)(gi - gj));
            }
#pragma unroll
            for (int off = 1; off < 16; off <<= 1)
                mx = fmaxf(mx, __shfl_xor(mx, off));
            if (r15 == 0) lst[wid >> 1][rowl][wid & 1][0] = mx;
        }
    __syncthreads();

    // pass 2: p_t = exp(v - tile-wide M_t); write Pt; row sums
    u16* ptb = Pt + (size_t)b * PT_BATCH + tri128(qt);
#pragma unroll
    for (int m = 0; m < 4; ++m)
#pragma unroll
        for (int r = 0; r < 4; ++r) {
            const int rowl = m * 16 + g4 * 4 + r;
            const int row = wr + rowl;
            const int gi = qt * 128 + row;
            const int im = lrepr[row];
            const float Mt = fmaxf(lst[wid >> 1][rowl][0][0], lst[wid >> 1][rowl][1][0]);
            float sm = 0.0f;
#pragma unroll
            for (int n = 0; n < 4; ++n) {
                const int col = wc + n * 16 + r15;
                const int gj = kt * 128 + col;
                const bool val = im && (gj < gi) && (lrepc[col] != 0);
                float pt = val ? __expf(acc[m][n][r] * scale - (float)(gi - gj) - Mt) : 0.0f;
                sm += pt;
                if (im) ptb[(size_t)row * nkq + kt * 128 + col] = f2bf(pt);
            }
#pragma unroll
            for (int off = 1; off < 16; off <<= 1)
                sm += __shfl_xor(sm, off);
            if (r15 == 0) lst[wid >> 1][rowl][wid & 1][1] = sm;
        }
    __syncthreads();
    if (tid < 128) {
        const int half = tid >> 6, row64 = tid & 63;
        float Mt = fmaxf(lst[half][row64][0][0], lst[half][row64][1][0]);
        float S = lst[half][row64][0][1] + lst[half][row64][1][1];
        st[(((size_t)b * 8 + kt) << 10) + qt * 128 + tid] = make_float2(Mt, S);
    }
}

// ===== pvsm2: GLD16 Pt + Vt; in-LDS scale (+attn fp32 write) -> MFMA -> out =====
__global__ __launch_bounds__(256) void pvsm2_kernel(const u16* __restrict__ Pt,
                                                    const float2* __restrict__ st,
                                                    const int* __restrict__ rep,
                                                    const u16* __restrict__ Vt,
                                                    float* __restrict__ attn,
                                                    float* __restrict__ out) {
    const int bid = blockIdx.x;
    const int xcd = bid & 7, w = bid >> 3;   // 0..63
    const int b = xcd * 2 + (w & 1);
    const int r_ = w >> 1;                   // 0..31
    const int dt = r_ & 3, qt = 7 - (r_ >> 2);   // LPT; 4 dt of a qt co-resident
    const int nk = (qt + 1) * 128;

    __shared__ u16 lA[128 * 64];
    __shared__ u16 lB[128 * 64];
    __shared__ float lC[128][8];

    const int tid = threadIdx.x, lane = tid & 63, wid = tid >> 6;
    const int l8 = lane >> 3, l7 = lane & 7;
    const int cswz = (l7 ^ l8) * 8;
    const int r15 = lane & 15, g4 = lane >> 4;

    if (tid < 128) {   // merge per-tile stats -> per-(row,kt) coefficient
        const int gi = qt * 128 + tid;
        float M = 0.0f, S = 0.0f;
        for (int kt = 0; kt <= qt; ++kt) {
            float2 ms = st[(((size_t)b * 8 + kt) << 10) + gi];
            float Mn = fmaxf(M, ms.x);
            S = S * __expf(M - Mn) + ms.y * __expf(ms.x - Mn);
            M = Mn;
        }
        const float inv = 1.0f / ((S == 0.0f ? 1.0f : S) + 1e-20f);
        const int mi = rep[(size_t)b * S_ + gi];
        for (int kt = 0; kt <= qt; ++kt) {
            float2 ms = st[(((size_t)b * 8 + kt) << 10) + gi];
            lC[tid][kt] = mi ? __expf(ms.x - M) * inv : 0.0f;   // 0 => exact zeros, kills poison
        }
    }
    __syncthreads();

    const u16* pts = Pt + (size_t)b * PT_BATCH + tri128(qt);
    const u16* bg = Vt + ((size_t)b * D_ + (size_t)dt * 128) * S_;
    const u16* ga[4];
    const u16* gb[4];
#pragma unroll
    for (int q2 = 0; q2 < 4; ++q2) {
        int seg = wid * 4 + q2;
        int row = seg * 8 + l8;
        ga[q2] = pts + (size_t)row * nk + cswz;
        gb[q2] = bg + (size_t)row * S_ + cswz;
    }
    const int au = tid & 7, ar0 = (tid >> 3) * 4;
    float* aw = attn + ((size_t)b * S_ + (size_t)qt * 128) * S_;

    f32x4 acc[4][4] = {};
    const int wr = (wid >> 1) * 64, wc = (wid & 1) * 64;
    const int cb = g4 * 16;

    for (int kk = 0; kk < nk; kk += 64) {
#pragma unroll
        for (int q2 = 0; q2 < 4; ++q2) {
            int seg = wid * 4 + q2;
            GLD16(ga[q2] + kk, lA + seg * 512);
            GLD16(gb[q2] + kk, lB + seg * 512);
        }
        __syncthreads();   // stage complete
        // in-LDS scale pass: p_t * cc; dt==0 also writes final P fp32
        const int ktc = kk >> 7;
#pragma unroll
        for (int rr = 0; rr < 4; ++rr) {
            const int row = ar0 + rr;
            u16* pl = (u16*)((char*)lA + row * 128 + ((au * 16) ^ ((row & 7) << 4)));
            union { s16x8 v; u16 h[8]; } pt;
            pt.v = *(const s16x8*)pl;
            const float cc = lC[row][ktc];
            float pf[8];
#pragma unroll
            for (int e = 0; e < 8; ++e) pf[e] = bf2f(pt.h[e]) * cc;
            if (dt == 0) {
                float* dst = aw + (size_t)row * S_ + kk + au * 8;
                *(float4*)dst = make_float4(pf[0], pf[1], pf[2], pf[3]);
                *(float4*)(dst + 4) = make_float4(pf[4], pf[5], pf[6], pf[7]);
            }
            union { ushort4 h[2]; s16x8 v; } rv;
            rv.h[0] = make_ushort4(f2bf(pf[0]), f2bf(pf[1]), f2bf(pf[2]), f2bf(pf[3]));
            rv.h[1] = make_ushort4(f2bf(pf[4]), f2bf(pf[5]), f2bf(pf[6]), f2bf(pf[7]));
            *(s16x8*)pl = rv.v;
        }
        __syncthreads();   // scaled tile visible
#pragma unroll
        for (int ks = 0; ks < 2; ++ks) {
            s16x8 af[4], bf4[4];
#pragma unroll
            for (int m = 0; m < 4; ++m) af[m] = frag_swz(lA, wr + m * 16 + r15, ks * 64 + cb);
#pragma unroll
            for (int n = 0; n < 4; ++n) bf4[n] = frag_swz(lB, wc + n * 16 + r15, ks * 64 + cb);
#pragma unroll
            for (int m = 0; m < 4; ++m)
#pragma unroll
                for (int n = 0; n < 4; ++n)
                    acc[m][n] = __builtin_amdgcn_mfma_f32_16x16x32_bf16(af[m], bf4[n], acc[m][n], 0, 0, 0);
        }
        __syncthreads();
    }

    if (dt == 1) {   // zero the causal tail of the attn stripe
        const int tail = S_ - nk;
        for (int t2 = tid * 4; t2 < 128 * tail; t2 += 1024) {
            int row = t2 / tail, c2 = t2 - row * tail;
            *(float4*)(aw + (size_t)row * S_ + nk + c2) = make_float4(0.f, 0.f, 0.f, 0.f);
        }
    }

    size_t base = ((size_t)b * S_ + (size_t)qt * 128) * D_ + (size_t)dt * 128;
    const int rr2 = (lane >> 4) * 4;
#pragma unroll
    for (int m = 0; m < 4; ++m)
#pragma unroll
        for (int n = 0; n < 4; ++n)
#pragma unroll
            for (int r = 0; r < 4; ++r)
                out[base + (size_t)(wr + m * 16 + rr2 + r) * D_ + wc + n * 16 + r15] =
                    acc[m][n][r];
}

// ======================= round-8 path (proven 90.0 us) =======================

__global__ __launch_bounds__(256) void qk2_kernel(const u16* __restrict__ Qb,
                                                  const u16* __restrict__ Kb,
                                                  const int* __restrict__ rep,
                                                  float* __restrict__ attn) {
    const int bid = blockIdx.x;
    const int xcd = bid & 7;
    const int w = bid >> 3;
    const int b = xcd * 2 + (w & 1);
    int p = 35 - (w >> 1);
    int qt = 0, tri = 0;
    while (p >= tri + qt + 1) { tri += qt + 1; ++qt; }
    const int kt = p - tri;

    __shared__ u16 lA[128 * 64];
    __shared__ u16 lB[128 * 64];
    __shared__ int lrepr[128];
    const int tid = threadIdx.x, lane = tid & 63, wid = tid >> 6;
    if (tid < 128) lrepr[tid] = rep[(size_t)b * S_ + qt * 128 + tid];

    f32x4 acc[4][4] = {};
    gemm_body(Qb + ((size_t)b * S_ + (size_t)qt * 128) * D_,
              Kb + ((size_t)b * S_ + (size_t)kt * 128) * D_,
              D_, D_, D_, lA, lB, acc, tid);
    const float scale = 0.04419417382415922f;
    const int wr = (wid >> 1) * 64, wc = (wid & 1) * 64;
    const int r15 = lane & 15, rr = (lane >> 4) * 4;
    size_t base = ((size_t)b * S_ + (size_t)qt * 128) * S_ + (size_t)kt * 128;
#pragma unroll
    for (int m = 0; m < 4; ++m)
#pragma unroll
        for (int r = 0; r < 4; ++r) {
            const int row = wr + m * 16 + rr + r;
            if (lrepr[row]) {
#pragma unroll
                for (int n = 0; n < 4; ++n)
                    attn[base + (size_t)row * S_ + wc + n * 16 + r15] =
                        acc[m][n][r] * scale;
            }
        }
}

__global__ __launch_bounds__(256) void pv2_kernel(const u16* __restrict__ Pb,
                                                  const u16* __restrict__ Vt,
                                                  float* __restrict__ out) {
    const int bid = blockIdx.x;
    const int xcd = bid & 7;
    const int w = bid >> 3;
    const int b = xcd * 2 + (w & 1);
    const int r = w >> 1;
    const int dt = r & 3, qt = 7 - (r >> 2);

    __shared__ u16 lA[128 * 64];
    __shared__ u16 lB[128 * 64];
    const int tid = threadIdx.x, lane = tid & 63, wid = tid >> 6;
    f32x4 acc[4][4] = {};
    gemm_body(Pb + ((size_t)b * S_ + (size_t)qt * 128) * S_,
              Vt + ((size_t)b * D_ + (size_t)dt * 128) * S_,
              S_, S_, (qt + 1) * 128, lA, lB, acc, tid);
    const int wr = (wid >> 1) * 64, wc = (wid & 1) * 64;
    const int r15 = lane & 15, rr = (lane >> 4) * 4;
    size_t base = ((size_t)b * S_ + (size_t)qt * 128) * D_ + (size_t)dt * 128;
#pragma unroll
    for (int m = 0; m < 4; ++m)
#pragma unroll
        for (int n = 0; n < 4; ++n)
#pragma unroll
            for (int rg = 0; rg < 4; ++rg)
                out[base + (size_t)(wr + m * 16 + rr + rg) * D_ + wc + n * 16 + r15] =
                    acc[m][n][rg];
}

__global__ __launch_bounds__(256) void sm_kernel(const int* __restrict__ rep_mask,
                                                 float* __restrict__ attn,
                                                 u16* __restrict__ pb) {
    const int i = blockIdx.x, b = blockIdx.y;
    const int tid = threadIdx.x;
    const int lane = tid & 63, wid = tid >> 6;
    float* row = attn + ((size_t)b * S_ + i) * S_;
    const int* rm = rep_mask + (size_t)b * S_;
    __shared__ float red[8];

    const int mi = rm[i];
    const int j0 = tid * 4;
    int4 m4 = ((const int4*)rm)[tid];
    float4 lv = make_float4(0.f, 0.f, 0.f, 0.f);
    if (mi != 0 && j0 < i) lv = *(const float4*)(row + j0);

    const int mv[4] = {m4.x, m4.y, m4.z, m4.w};
    const float lf[4] = {lv.x, lv.y, lv.z, lv.w};
    float vec[4];
    bool val[4];
    float mymax = 0.0f;
#pragma unroll
    for (int e = 0; e < 4; ++e) {
        int j = j0 + e;
        val[e] = (mi != 0) && (j < i) && (mv[e] != 0);
        vec[e] = lf[e] - (float)(i - j);
        if (val[e]) mymax = fmaxf(mymax, vec[e]);
    }
#pragma unroll
    for (int off = 32; off > 0; off >>= 1) mymax = fmaxf(mymax, __shfl_down(mymax, off));
    if (lane == 0) red[wid] = mymax;
    __syncthreads();
    const float m = fmaxf(fmaxf(red[0], red[1]), fmaxf(red[2], red[3]));

    float ex[4];
    float mysum = 0.0f;
#pragma unroll
    for (int e = 0; e < 4; ++e) {
        ex[e] = val[e] ? expf(vec[e] - m) : 0.0f;
        mysum += ex[e];
    }
#pragma unroll
    for (int off = 32; off > 0; off >>= 1) mysum += __shfl_down(mysum, off);
    if (lane == 0) red[4 + wid] = mysum;
    __syncthreads();
    const float ssum = red[4] + red[5] + red[6] + red[7];
    const float denom = ssum + (ssum == 0.0f ? 1.0f : 0.0f) + 1e-20f;
    const float inv = 1.0f / denom;
    float4 o = make_float4(ex[0] * inv, ex[1] * inv, ex[2] * inv, ex[3] * inv);
    *(float4*)(row + j0) = o;
    if (pb != nullptr && j0 <= (i | 127)) {
        u16* pr = pb + ((size_t)b * S_ + i) * S_ + j0;
        *(ushort4*)pr = make_ushort4(f2bf(o.x), f2bf(o.y), f2bf(o.z), f2bf(o.w));
    }
}

// ======================= legacy fallback path (no ws) =======================

union Frag { s16x8 v; uint2 u[2]; };

__device__ __forceinline__ s16x8 load_frag(const u16* lds, int row, int kq) {
    Frag f;
    const u16* p = lds + row * PITCH + kq;
    f.u[0] = *(const uint2*)p;
    f.u[1] = *(const uint2*)(p + 4);
    return f.v;
}

__device__ __forceinline__ void stage_granule(u16* lds, const float* src, int ldsrc, int g) {
    int row = g >> 2;
    int c8 = (g & 3) * 8;
    const float4* s = (const float4*)(src + (size_t)row * ldsrc + c8);
    float4 x0 = s[0], x1 = s[1];
    *(ushort4*)(lds + row * PITCH + c8) =
        make_ushort4(f2bf(x0.x), f2bf(x0.y), f2bf(x0.z), f2bf(x0.w));
    *(ushort4*)(lds + row * PITCH + c8 + 4) =
        make_ushort4(f2bf(x1.x), f2bf(x1.y), f2bf(x1.z), f2bf(x1.w));
}

__global__ __launch_bounds__(256) void qk_kernel(const float* __restrict__ q,
                                                 const float* __restrict__ k,
                                                 float* __restrict__ attn) {
    const int kt = blockIdx.x, qt = blockIdx.y, b = blockIdx.z;
    if (kt > qt) return;
    __shared__ u16 lA[TILE * PITCH];
    __shared__ u16 lB[TILE * PITCH];
    const int tid = threadIdx.x;
    const int lane = tid & 63;
    const int wid = tid >> 6;
    const int wr = (wid >> 1) * 64, wc = (wid & 1) * 64;
    const int r15 = lane & 15, kq = (lane >> 4) * 8;
    const float* qb = q + ((size_t)b * S_ + (size_t)qt * TILE) * D_;
    const float* kb = k + ((size_t)b * S_ + (size_t)kt * TILE) * D_;
    f32x4 acc[4][4] = {};
    for (int kk = 0; kk < D_; kk += BK) {
        __syncthreads();
        stage_granule(lA, qb + kk, D_, tid);
        stage_granule(lA, qb + kk, D_, tid + 256);
        stage_granule(lB, kb + kk, D_, tid);
        stage_granule(lB, kb + kk, D_, tid + 256);
        __syncthreads();
        s16x8 af[4], bf[4];
#pragma unroll
        for (int m = 0; m < 4; ++m) af[m] = load_frag(lA, wr + m * 16 + r15, kq);
#pragma unroll
        for (int n = 0; n < 4; ++n) bf[n] = load_frag(lB, wc + n * 16 + r15, kq);
#pragma unroll
        for (int m = 0; m < 4; ++m)
#pragma unroll
            for (int n = 0; n < 4; ++n)
                acc[m][n] = __builtin_amdgcn_mfma_f32_16x16x32_bf16(af[m], bf[n], acc[m][n], 0, 0, 0);
    }
    const float scale = 0.04419417382415922f;
    size_t base = ((size_t)b * S_ + (size_t)qt * TILE) * S_ + (size_t)kt * TILE;
    const int rr = (lane >> 4) * 4;
#pragma unroll
    for (int m = 0; m < 4; ++m)
#pragma unroll
        for (int n = 0; n < 4; ++n)
#pragma unroll
            for (int r = 0; r < 4; ++r)
                attn[base + (size_t)(wr + m * 16 + rr + r) * S_ + wc + n * 16 + r15] =
                    acc[m][n][r] * scale;
}

__global__ __launch_bounds__(256) void pv_kernel(const float* __restrict__ attn,
                                                 const float* __restrict__ v,
                                                 float* __restrict__ out) {
    const int dt = blockIdx.x, qt = blockIdx.y, b = blockIdx.z;
    __shared__ u16 lP[TILE * PITCH];
    __shared__ u16 lV[TILE * PITCH];
    const int tid = threadIdx.x;
    const int lane = tid & 63;
    const int wid = tid >> 6;
    const int wr = (wid >> 1) * 64, wc = (wid & 1) * 64;
    const int r15 = lane & 15, kq = (lane >> 4) * 8;
    const float* pb = attn + ((size_t)b * S_ + (size_t)qt * TILE) * S_;
    const float* vb = v + (size_t)b * S_ * D_ + (size_t)dt * TILE;
    const int vd0 = (tid & 31) * 4;
    const int vj0 = (tid >> 5) * 4;
    f32x4 acc[4][4] = {};
    const int nk = (qt + 1) * TILE;
    for (int kk = 0; kk < nk; kk += BK) {
        __syncthreads();
        stage_granule(lP, pb + kk, S_, tid);
        stage_granule(lP, pb + kk, S_, tid + 256);
        {
            const float* vs = vb + (size_t)(kk + vj0) * D_ + vd0;
            float4 r0 = *(const float4*)vs;
            float4 r1 = *(const float4*)(vs + D_);
            float4 r2 = *(const float4*)(vs + 2 * D_);
            float4 r3 = *(const float4*)(vs + 3 * D_);
            *(ushort4*)(lV + (vd0 + 0) * PITCH + vj0) = make_ushort4(f2bf(r0.x), f2bf(r1.x), f2bf(r2.x), f2bf(r3.x));
            *(ushort4*)(lV + (vd0 + 1) * PITCH + vj0) = make_ushort4(f2bf(r0.y), f2bf(r1.y), f2bf(r2.y), f2bf(r3.y));
            *(ushort4*)(lV + (vd0 + 2) * PITCH + vj0) = make_ushort4(f2bf(r0.z), f2bf(r1.z), f2bf(r2.z), f2bf(r3.z));
            *(ushort4*)(lV + (vd0 + 3) * PITCH + vj0) = make_ushort4(f2bf(r0.w), f2bf(r1.w), f2bf(r2.w), f2bf(r3.w));
        }
        __syncthreads();
        s16x8 af[4], bf[4];
#pragma unroll
        for (int m = 0; m < 4; ++m) af[m] = load_frag(lP, wr + m * 16 + r15, kq);
#pragma unroll
        for (int n = 0; n < 4; ++n) bf[n] = load_frag(lV, wc + n * 16 + r15, kq);
#pragma unroll
        for (int m = 0; m < 4; ++m)
#pragma unroll
            for (int n = 0; n < 4; ++n)
                acc[m][n] = __builtin_amdgcn_mfma_f32_16x16x32_bf16(af[m], bf[n], acc[m][n], 0, 0, 0);
    }
    size_t base = ((size_t)b * S_ + (size_t)qt * TILE) * D_ + (size_t)dt * TILE;
    const int rr = (lane >> 4) * 4;
#pragma unroll
    for (int m = 0; m < 4; ++m)
#pragma unroll
        for (int n = 0; n < 4; ++n)
#pragma unroll
            for (int r = 0; r < 4; ++r)
                out[base + (size_t)(wr + m * 16 + rr + r) * D_ + wc + n * 16 + r15] =
                    acc[m][n][r];
}

extern "C" void kernel_launch(void* const* d_in, const int* in_sizes, int n_in,
                              void* d_out, int out_size, void* d_ws, size_t ws_size,
                              hipStream_t stream) {
    const float* q = (const float*)d_in[0];
    const float* k = (const float*)d_in[1];
    const float* v = (const float*)d_in[2];
    const int* rep = (const int*)d_in[3];
    float* out = (float*)d_out;
    float* attn = out + (size_t)B_ * S_ * D_;   // second output region [B,S,S]

    const size_t nqk = (size_t)B_ * S_ * D_;        // 8.4M
    const size_t npt = (size_t)B_ * PT_BATCH;       // 9.4M
    const size_t nst = (size_t)B_ * 8 * S_;         // stats float2
    const size_t need_new = 3 * nqk * sizeof(u16) + npt * sizeof(u16) + nst * sizeof(float2); // 70.3 MB
    const size_t need_r8 = 3 * nqk * sizeof(u16);   // 50.3 MB (confirmed available)

    if (ws_size >= need_new) {
        u16* Qb = (u16*)d_ws;
        u16* Kb = Qb + nqk;
        u16* Vt = Kb + nqk;
        u16* Pt = Vt + nqk;
        float2* st = (float2*)(Pt + npt);
        prep_kernel<<<10240, 256, 0, stream>>>(q, k, v, Qb, Kb, Vt);
        qk4_kernel<<<8 * 72, 256, 0, stream>>>(Qb, Kb, rep, Pt, st);
        pvsm2_kernel<<<8 * 64, 256, 0, stream>>>(Pt, st, rep, Vt, attn, out);
    } else if (ws_size >= need_r8) {
        u16* Qb = (u16*)d_ws;
        u16* Kb = Qb + nqk;
        u16* Vt = Kb + nqk;
        u16* Pb = (u16*)d_ws;   // aliases Qb+Kb; dead after qk2
        prep_kernel<<<10240, 256, 0, stream>>>(q, k, v, Qb, Kb, Vt);
        qk2_kernel<<<8 * 72, 256, 0, stream>>>(Qb, Kb, rep, attn);
        sm_kernel<<<dim3(S_, B_), 256, 0, stream>>>(rep, attn, Pb);
        pv2_kernel<<<8 * 64, 256, 0, stream>>>(Pb, Vt, out);
    } else {
        qk_kernel<<<dim3(S_ / TILE, S_ / TILE, B_), 256, 0, stream>>>(q, k, attn);
        sm_kernel<<<dim3(S_, B_), 256, 0, stream>>>(rep, attn, nullptr);
        pv_kernel<<<dim3(D_ / TILE, S_ / TILE, B_), 256, 0, stream>>>(attn, v, out);
    }
}

// Round 12
// 106.194 us; speedup vs baseline: 1.2240x; 1.2240x over previous
//
#include <hip/hip_runtime.h>
#include <cstdint>

#define B_ 16
#define S_ 1024
#define D_ 512
#define TILE 128
#define BK 32
#define PITCH 36   // legacy-path LDS pitch

typedef float f32x4 __attribute__((ext_vector_type(4)));
typedef short s16x8 __attribute__((ext_vector_type(8)));
typedef unsigned short u16;
typedef unsigned int u32;

__device__ __forceinline__ u16 f2bf(float f) {
    u32 u = __builtin_bit_cast(u32, f);
    u += 0x7FFFu + ((u >> 16) & 1u);
    return (u16)(u >> 16);
}
__device__ __forceinline__ float bf2f(u16 h) {
    return __builtin_bit_cast(float, (u32)h << 16);
}

#define GLD16(g, l) __builtin_amdgcn_global_load_lds( \
    (const __attribute__((address_space(1))) u32*)(g), \
    (__attribute__((address_space(3))) u32*)(l), 16, 0, 0)

// per-batch compact causal P_t elems: sum_qt (qt+1)*128*128 = 589824
#define PT_BATCH 589824
__device__ __forceinline__ int tri128(int qt) { return ((qt * (qt + 1)) >> 1) * 16384; }

// ===== prep: cvt(Q) + cvt(K) + transpose-cvt(V) (round-8 proven) =====
#define TP 66
__global__ __launch_bounds__(256) void prep_kernel(const float* __restrict__ q,
                                                   const float* __restrict__ k,
                                                   const float* __restrict__ v,
                                                   u16* __restrict__ Qb,
                                                   u16* __restrict__ Kb,
                                                   u16* __restrict__ Vt) {
    __shared__ u16 t[64 * TP];
    const int bid = blockIdx.x;
    const int tid = threadIdx.x;
    if (bid < 8192) {
        const float* src = (bid < 4096) ? q : k;
        u16* dst = (bid < 4096) ? Qb : Kb;
        int i = (((bid & 4095) * 256) + tid) * 8;
        float4 a = *(const float4*)(src + i);
        float4 b2 = *(const float4*)(src + i + 4);
        union { ushort4 h[2]; s16x8 v; } r;
        r.h[0] = make_ushort4(f2bf(a.x), f2bf(a.y), f2bf(a.z), f2bf(a.w));
        r.h[1] = make_ushort4(f2bf(b2.x), f2bf(b2.y), f2bf(b2.z), f2bf(b2.w));
        *(s16x8*)(dst + i) = r.v;
    } else {
        int tt = bid - 8192;
        const int d0 = (tt & 7) * 64, j0 = ((tt >> 3) & 15) * 64, b = tt >> 7;
        const int tj = tid >> 2;
        const int td = (tid & 3) * 16;
        const float* src = v + ((size_t)b * S_ + j0 + tj) * D_ + d0 + td;
#pragma unroll
        for (int e = 0; e < 4; ++e) {
            float4 a = *(const float4*)(src + e * 4);
            *(ushort4*)(t + tj * TP + td + e * 4) =
                make_ushort4(f2bf(a.x), f2bf(a.y), f2bf(a.z), f2bf(a.w));
        }
        __syncthreads();
        const int dd = tid >> 2;
        const int jj = (tid & 3) * 16;
        u16* dstp = Vt + ((size_t)b * D_ + d0 + dd) * S_ + j0 + jj;
        u16 tmp[16];
#pragma unroll
        for (int e = 0; e < 16; ++e) tmp[e] = t[(jj + e) * TP + dd];
        *(s16x8*)dstp = *(s16x8*)tmp;
        *(s16x8*)(dstp + 8) = *(s16x8*)(tmp + 8);
    }
}

// swizzled LDS read: logical [row][col(64 bf16)] stored with byte ^= (row&7)<<4
__device__ __forceinline__ s16x8 frag_swz(const u16* lds, int row, int colbyte) {
    int off = row * 128 + (colbyte ^ ((row & 7) << 4));
    return *(const s16x8*)((const char*)lds + off);
}

// m97-style bf16 GEMM tile body (proven): 128x128, BK=64, global_load_lds + swizzle
__device__ __forceinline__ void gemm_body(const u16* ag, const u16* bg, int lda, int ldb,
                                          int nk, u16* lA, u16* lB, f32x4 acc[4][4],
                                          int tid) {
    const int lane = tid & 63, wid = tid >> 6;
    const int l8 = lane >> 3, l7 = lane & 7;
    const int cswz = (l7 ^ l8) * 8;
    const u16* ga[4];
    const u16* gb[4];
#pragma unroll
    for (int q2 = 0; q2 < 4; ++q2) {
        int seg = wid * 4 + q2;
        int row = seg * 8 + l8;
        ga[q2] = ag + (size_t)row * lda + cswz;
        gb[q2] = bg + (size_t)row * ldb + cswz;
    }
    const int wr = (wid >> 1) * 64, wc = (wid & 1) * 64;
    const int r15 = lane & 15;
    const int cb = (lane >> 4) * 16;

    for (int kk = 0; kk < nk; kk += 64) {
#pragma unroll
        for (int q2 = 0; q2 < 4; ++q2) {
            int seg = wid * 4 + q2;
            GLD16(ga[q2] + kk, lA + seg * 512);
            GLD16(gb[q2] + kk, lB + seg * 512);
        }
        __syncthreads();
#pragma unroll
        for (int ks = 0; ks < 2; ++ks) {
            s16x8 af[4], bf4[4];
#pragma unroll
            for (int m = 0; m < 4; ++m) af[m] = frag_swz(lA, wr + m * 16 + r15, ks * 64 + cb);
#pragma unroll
            for (int n = 0; n < 4; ++n) bf4[n] = frag_swz(lB, wc + n * 16 + r15, ks * 64 + cb);
#pragma unroll
            for (int m = 0; m < 4; ++m)
#pragma unroll
                for (int n = 0; n < 4; ++n)
                    acc[m][n] = __builtin_amdgcn_mfma_f32_16x16x32_bf16(af[m], bf4[n], acc[m][n], 0, 0, 0);
        }
        __syncthreads();
    }
}

// ===== qk4: gemm_body + exp epilogue; Pt staged in LDS and stored coalesced =====
__global__ __launch_bounds__(256) void qk4_kernel(const u16* __restrict__ Qb,
                                                  const u16* __restrict__ Kb,
                                                  const int* __restrict__ rep,
                                                  u16* __restrict__ Pt,
                                                  float2* __restrict__ st) {
    const int bid = blockIdx.x;
    const int xcd = bid & 7;
    const int w = bid >> 3;            // 0..71
    const int b = xcd * 2 + (w & 1);
    int p = 35 - (w >> 1);             // LPT
    int qt = 0, tri = 0;
    while (p >= tri + qt + 1) { tri += qt + 1; ++qt; }
    const int kt = p - tri;
    const int nkq = (qt + 1) * 128;

    __shared__ u16 lA[128 * 64];
    __shared__ u16 lB[128 * 64];
    __shared__ int lrepr[128];
    __shared__ int lrepc[128];
    __shared__ float lst[2][64][2][2];   // [row half][row64][col half][max/sum]

    const int tid = threadIdx.x, lane = tid & 63, wid = tid >> 6;
    const int r15 = lane & 15, g4 = lane >> 4;
    if (tid < 128) lrepr[tid] = rep[(size_t)b * S_ + qt * 128 + tid];
    else lrepc[tid - 128] = rep[(size_t)b * S_ + kt * 128 + (tid - 128)];

    f32x4 acc[4][4] = {};
    gemm_body(Qb + ((size_t)b * S_ + (size_t)qt * 128) * D_,
              Kb + ((size_t)b * S_ + (size_t)kt * 128) * D_,
              D_, D_, D_, lA, lB, acc, tid);

    const float scale = 0.04419417382415922f;  // 1/sqrt(512)
    const int wr = (wid >> 1) * 64, wc = (wid & 1) * 64;

    // pass 1: FULL-tile row max (both column halves)
#pragma unroll
    for (int m = 0; m < 4; ++m)
#pragma unroll
        for (int r = 0; r < 4; ++r) {
            const int rowl = m * 16 + g4 * 4 + r;
            const int row = wr + rowl;
            const int gi = qt * 128 + row;
            const int im = lrepr[row];
            float mx = 0.0f;   // masked entries contribute 0 to the max (reference)
#pragma unroll
            for (int n = 0; n < 4; ++n) {
                const int col = wc + n * 16 + r15;
                const int gj = kt * 128 + col;
                if (im && (gj < gi) && (lrepc[col] != 0))
                    mx = fmaxf(mx, acc[m][n][r] * scale - (float)(gi - gj));
            }
#pragma unroll
            for (int off = 1; off < 16; off <<= 1)
                mx = fmaxf(mx, __shfl_xor(mx, off));
            if (r15 == 0) lst[wid >> 1][rowl][wid & 1][0] = mx;
        }
    __syncthreads();

    // pass 2: p_t = exp(v - tile-wide M_t) -> LDS tile [row][128]; row sums
#pragma unroll
    for (int m = 0; m < 4; ++m)
#pragma unroll
        for (int r = 0; r < 4; ++r) {
            const int rowl = m * 16 + g4 * 4 + r;
            const int row = wr + rowl;
            const int gi = qt * 128 + row;
            const int im = lrepr[row];
            const float Mt = fmaxf(lst[wid >> 1][rowl][0][0], lst[wid >> 1][rowl][1][0]);
            float sm = 0.0f;
#pragma unroll
            for (int n = 0; n < 4; ++n) {
                const int col = wc + n * 16 + r15;
                const int gj = kt * 128 + col;
                const bool val = im && (gj < gi) && (lrepc[col] != 0);
                float pt = val ? __expf(acc[m][n][r] * scale - (float)(gi - gj) - Mt) : 0.0f;
                sm += pt;
                u16* ptile = (col < 64) ? lA : lB;
                ptile[row * 64 + (col & 63)] = f2bf(pt);   // zeros for masked too
            }
#pragma unroll
            for (int off = 1; off < 16; off <<= 1)
                sm += __shfl_xor(sm, off);
            if (r15 == 0) lst[wid >> 1][rowl][wid & 1][1] = sm;
        }
    __syncthreads();

    // coalesced Pt copy-out: 16B per store, 8 stores/thread
    u16* ptb = Pt + (size_t)b * PT_BATCH + tri128(qt) + kt * 128;
#pragma unroll
    for (int e = 0; e < 8; ++e) {
        int gid = e * 256 + tid;          // 0..2047
        int row = gid >> 4;
        int colg = (gid & 15) * 8;
        const u16* src = ((colg < 64) ? lA : lB) + row * 64 + (colg & 63);
        *(s16x8*)(ptb + (size_t)row * nkq + colg) = *(const s16x8*)src;
    }
    if (tid < 128) {
        const int half = tid >> 6, row64 = tid & 63;
        float Mt = fmaxf(lst[half][row64][0][0], lst[half][row64][1][0]);
        float S = lst[half][row64][0][1] + lst[half][row64][1][1];
        st[(((size_t)b * 8 + kt) << 10) + qt * 128 + tid] = make_float2(Mt, S);
    }
}

// ===== pvsm3: 2-barrier loop; per-chunk tmp acc + cc merge; balanced attn write =====
__global__ __launch_bounds__(256) void pvsm3_kernel(const u16* __restrict__ Pt,
                                                    const float2* __restrict__ st,
                                                    const int* __restrict__ rep,
                                                    const u16* __restrict__ Vt,
                                                    float* __restrict__ attn,
                                                    float* __restrict__ out) {
    const int bid = blockIdx.x;
    const int xcd = bid & 7, w = bid >> 3;   // 0..63
    const int b = xcd * 2 + (w & 1);
    const int r_ = w >> 1;                   // 0..31
    const int dt = r_ & 3, qt = 7 - (r_ >> 2);   // LPT; 4 dt of a qt co-resident
    const int nk = (qt + 1) * 128;

    __shared__ u16 lA[128 * 64];
    __shared__ u16 lB[128 * 64];
    __shared__ float lC[128][8];

    const int tid = threadIdx.x, lane = tid & 63, wid = tid >> 6;
    const int l8 = lane >> 3, l7 = lane & 7;
    const int cswz = (l7 ^ l8) * 8;
    const int r15 = lane & 15, g4 = lane >> 4;

    if (tid < 128) {   // merge per-tile stats -> per-(row,kt) coefficient
        const int gi = qt * 128 + tid;
        float M = 0.0f, S = 0.0f;
        for (int kt = 0; kt <= qt; ++kt) {
            float2 ms = st[(((size_t)b * 8 + kt) << 10) + gi];
            float Mn = fmaxf(M, ms.x);
            S = S * __expf(M - Mn) + ms.y * __expf(ms.x - Mn);
            M = Mn;
        }
        const float inv = 1.0f / ((S == 0.0f ? 1.0f : S) + 1e-20f);
        const int mi = rep[(size_t)b * S_ + gi];
        for (int kt = 0; kt <= qt; ++kt) {
            float2 ms = st[(((size_t)b * 8 + kt) << 10) + gi];
            lC[tid][kt] = mi ? __expf(ms.x - M) * inv : 0.0f;
        }
    }
    __syncthreads();

    const u16* pts = Pt + (size_t)b * PT_BATCH + tri128(qt);
    const u16* bg = Vt + ((size_t)b * D_ + (size_t)dt * 128) * S_;
    const u16* ga[4];
    const u16* gb[4];
#pragma unroll
    for (int q2 = 0; q2 < 4; ++q2) {
        int seg = wid * 4 + q2;
        int row = seg * 8 + l8;
        ga[q2] = pts + (size_t)row * nk + cswz;
        gb[q2] = bg + (size_t)row * S_ + cswz;
    }
    const int au = tid & 7, ar0 = (tid >> 3) * 4;
    float* aw = attn + ((size_t)b * S_ + (size_t)qt * 128) * S_;

    f32x4 acc[4][4] = {};
    const int wr = (wid >> 1) * 64, wc = (wid & 1) * 64;
    const int cb = g4 * 16;
    const int rr4 = g4 * 4;

    for (int kc = 0; kc < nk; kc += 128) {   // one kt chunk = 2 K-steps
        const int ktc = kc >> 7;
        f32x4 tmp[4][4] = {};
#pragma unroll
        for (int half = 0; half < 2; ++half) {
            const int kk = kc + half * 64;
#pragma unroll
            for (int q2 = 0; q2 < 4; ++q2) {
                int seg = wid * 4 + q2;
                GLD16(ga[q2] + kk, lA + seg * 512);
                GLD16(gb[q2] + kk, lB + seg * 512);
            }
            __syncthreads();   // stage complete
            if (((kk >> 6) & 3) == dt) {   // balanced attn fp32 write (scaled)
#pragma unroll
                for (int rr = 0; rr < 4; ++rr) {
                    const int row = ar0 + rr;
                    union { s16x8 v; u16 h[8]; } pt;
                    pt.v = *(const s16x8*)(lA + row * 64 + ((au ^ (row & 7)) * 8));
                    const float cc = lC[row][ktc];
                    float* dst = aw + (size_t)row * S_ + kk + au * 8;
                    *(float4*)dst = make_float4(bf2f(pt.h[0]) * cc, bf2f(pt.h[1]) * cc,
                                                bf2f(pt.h[2]) * cc, bf2f(pt.h[3]) * cc);
                    *(float4*)(dst + 4) = make_float4(bf2f(pt.h[4]) * cc, bf2f(pt.h[5]) * cc,
                                                      bf2f(pt.h[6]) * cc, bf2f(pt.h[7]) * cc);
                }
            }
#pragma unroll
            for (int ks = 0; ks < 2; ++ks) {
                s16x8 af[4], bf4[4];
#pragma unroll
                for (int m = 0; m < 4; ++m) af[m] = frag_swz(lA, wr + m * 16 + r15, ks * 64 + cb);
#pragma unroll
                for (int n = 0; n < 4; ++n) bf4[n] = frag_swz(lB, wc + n * 16 + r15, ks * 64 + cb);
#pragma unroll
                for (int m = 0; m < 4; ++m)
#pragma unroll
                    for (int n = 0; n < 4; ++n)
                        tmp[m][n] = __builtin_amdgcn_mfma_f32_16x16x32_bf16(af[m], bf4[n], tmp[m][n], 0, 0, 0);
            }
            __syncthreads();
        }
        // merge chunk: acc += cc[row][ktc] * tmp  (LDS broadcast reads)
#pragma unroll
        for (int m = 0; m < 4; ++m)
#pragma unroll
            for (int r2 = 0; r2 < 4; ++r2) {
                const float cc = lC[wr + m * 16 + rr4 + r2][ktc];
#pragma unroll
                for (int n = 0; n < 4; ++n)
                    acc[m][n][r2] += cc * tmp[m][n][r2];
            }
    }

    if (dt == 1) {   // zero the causal tail of the attn stripe
        const int tail = S_ - nk;
        for (int t2 = tid * 4; t2 < 128 * tail; t2 += 1024) {
            int row = t2 / tail, c2 = t2 - row * tail;
            *(float4*)(aw + (size_t)row * S_ + nk + c2) = make_float4(0.f, 0.f, 0.f, 0.f);
        }
    }

    size_t base = ((size_t)b * S_ + (size_t)qt * 128) * D_ + (size_t)dt * 128;
#pragma unroll
    for (int m = 0; m < 4; ++m)
#pragma unroll
        for (int n = 0; n < 4; ++n)
#pragma unroll
            for (int r = 0; r < 4; ++r)
                out[base + (size_t)(wr + m * 16 + rr4 + r) * D_ + wc + n * 16 + r15] =
                    acc[m][n][r];
}

// ======================= round-8 path (proven 90.0 us) =======================

__global__ __launch_bounds__(256) void qk2_kernel(const u16* __restrict__ Qb,
                                                  const u16* __restrict__ Kb,
                                                  const int* __restrict__ rep,
                                                  float* __restrict__ attn) {
    const int bid = blockIdx.x;
    const int xcd = bid & 7;
    const int w = bid >> 3;
    const int b = xcd * 2 + (w & 1);
    int p = 35 - (w >> 1);
    int qt = 0, tri = 0;
    while (p >= tri + qt + 1) { tri += qt + 1; ++qt; }
    const int kt = p - tri;

    __shared__ u16 lA[128 * 64];
    __shared__ u16 lB[128 * 64];
    __shared__ int lrepr[128];
    const int tid = threadIdx.x, lane = tid & 63, wid = tid >> 6;
    if (tid < 128) lrepr[tid] = rep[(size_t)b * S_ + qt * 128 + tid];

    f32x4 acc[4][4] = {};
    gemm_body(Qb + ((size_t)b * S_ + (size_t)qt * 128) * D_,
              Kb + ((size_t)b * S_ + (size_t)kt * 128) * D_,
              D_, D_, D_, lA, lB, acc, tid);
    const float scale = 0.04419417382415922f;
    const int wr = (wid >> 1) * 64, wc = (wid & 1) * 64;
    const int r15 = lane & 15, rr = (lane >> 4) * 4;
    size_t base = ((size_t)b * S_ + (size_t)qt * 128) * S_ + (size_t)kt * 128;
#pragma unroll
    for (int m = 0; m < 4; ++m)
#pragma unroll
        for (int r = 0; r < 4; ++r) {
            const int row = wr + m * 16 + rr + r;
            if (lrepr[row]) {
#pragma unroll
                for (int n = 0; n < 4; ++n)
                    attn[base + (size_t)row * S_ + wc + n * 16 + r15] =
                        acc[m][n][r] * scale;
            }
        }
}

__global__ __launch_bounds__(256) void pv2_kernel(const u16* __restrict__ Pb,
                                                  const u16* __restrict__ Vt,
                                                  float* __restrict__ out) {
    const int bid = blockIdx.x;
    const int xcd = bid & 7;
    const int w = bid >> 3;
    const int b = xcd * 2 + (w & 1);
    const int r = w >> 1;
    const int dt = r & 3, qt = 7 - (r >> 2);

    __shared__ u16 lA[128 * 64];
    __shared__ u16 lB[128 * 64];
    const int tid = threadIdx.x, lane = tid & 63, wid = tid >> 6;
    f32x4 acc[4][4] = {};
    gemm_body(Pb + ((size_t)b * S_ + (size_t)qt * 128) * S_,
              Vt + ((size_t)b * D_ + (size_t)dt * 128) * S_,
              S_, S_, (qt + 1) * 128, lA, lB, acc, tid);
    const int wr = (wid >> 1) * 64, wc = (wid & 1) * 64;
    const int r15 = lane & 15, rr = (lane >> 4) * 4;
    size_t base = ((size_t)b * S_ + (size_t)qt * 128) * D_ + (size_t)dt * 128;
#pragma unroll
    for (int m = 0; m < 4; ++m)
#pragma unroll
        for (int n = 0; n < 4; ++n)
#pragma unroll
            for (int rg = 0; rg < 4; ++rg)
                out[base + (size_t)(wr + m * 16 + rr + rg) * D_ + wc + n * 16 + r15] =
                    acc[m][n][rg];
}

__global__ __launch_bounds__(256) void sm_kernel(const int* __restrict__ rep_mask,
                                                 float* __restrict__ attn,
                                                 u16* __restrict__ pb) {
    const int i = blockIdx.x, b = blockIdx.y;
    const int tid = threadIdx.x;
    const int lane = tid & 63, wid = tid >> 6;
    float* row = attn + ((size_t)b * S_ + i) * S_;
    const int* rm = rep_mask + (size_t)b * S_;
    __shared__ float red[8];

    const int mi = rm[i];
    const int j0 = tid * 4;
    int4 m4 = ((const int4*)rm)[tid];
    float4 lv = make_float4(0.f, 0.f, 0.f, 0.f);
    if (mi != 0 && j0 < i) lv = *(const float4*)(row + j0);

    const int mv[4] = {m4.x, m4.y, m4.z, m4.w};
    const float lf[4] = {lv.x, lv.y, lv.z, lv.w};
    float vec[4];
    bool val[4];
    float mymax = 0.0f;
#pragma unroll
    for (int e = 0; e < 4; ++e) {
        int j = j0 + e;
        val[e] = (mi != 0) && (j < i) && (mv[e] != 0);
        vec[e] = lf[e] - (float)(i - j);
        if (val[e]) mymax = fmaxf(mymax, vec[e]);
    }
#pragma unroll
    for (int off = 32; off > 0; off >>= 1) mymax = fmaxf(mymax, __shfl_down(mymax, off));
    if (lane == 0) red[wid] = mymax;
    __syncthreads();
    const float m = fmaxf(fmaxf(red[0], red[1]), fmaxf(red[2], red[3]));

    float ex[4];
    float mysum = 0.0f;
#pragma unroll
    for (int e = 0; e < 4; ++e) {
        ex[e] = val[e] ? expf(vec[e] - m) : 0.0f;
        mysum += ex[e];
    }
#pragma unroll
    for (int off = 32; off > 0; off >>= 1) mysum += __shfl_down(mysum, off);
    if (lane == 0) red[4 + wid] = mysum;
    __syncthreads();
    const float ssum = red[4] + red[5] + red[6] + red[7];
    const float denom = ssum + (ssum == 0.0f ? 1.0f : 0.0f) + 1e-20f;
    const float inv = 1.0f / denom;
    float4 o = make_float4(ex[0] * inv, ex[1] * inv, ex[2] * inv, ex[3] * inv);
    *(float4*)(row + j0) = o;
    if (pb != nullptr && j0 <= (i | 127)) {
        u16* pr = pb + ((size_t)b * S_ + i) * S_ + j0;
        *(ushort4*)pr = make_ushort4(f2bf(o.x), f2bf(o.y), f2bf(o.z), f2bf(o.w));
    }
}

// ======================= legacy fallback path (no ws) =======================

union Frag { s16x8 v; uint2 u[2]; };

__device__ __forceinline__ s16x8 load_frag(const u16* lds, int row, int kq) {
    Frag f;
    const u16* p = lds + row * PITCH + kq;
    f.u[0] = *(const uint2*)p;
    f.u[1] = *(const uint2*)(p + 4);
    return f.v;
}

__device__ __forceinline__ void stage_granule(u16* lds, const float* src, int ldsrc, int g) {
    int row = g >> 2;
    int c8 = (g & 3) * 8;
    const float4* s = (const float4*)(src + (size_t)row * ldsrc + c8);
    float4 x0 = s[0], x1 = s[1];
    *(ushort4*)(lds + row * PITCH + c8) =
        make_ushort4(f2bf(x0.x), f2bf(x0.y), f2bf(x0.z), f2bf(x0.w));
    *(ushort4*)(lds + row * PITCH + c8 + 4) =
        make_ushort4(f2bf(x1.x), f2bf(x1.y), f2bf(x1.z), f2bf(x1.w));
}

__global__ __launch_bounds__(256) void qk_kernel(const float* __restrict__ q,
                                                 const float* __restrict__ k,
                                                 float* __restrict__ attn) {
    const int kt = blockIdx.x, qt = blockIdx.y, b = blockIdx.z;
    if (kt > qt) return;
    __shared__ u16 lA[TILE * PITCH];
    __shared__ u16 lB[TILE * PITCH];
    const int tid = threadIdx.x;
    const int lane = tid & 63;
    const int wid = tid >> 6;
    const int wr = (wid >> 1) * 64, wc = (wid & 1) * 64;
    const int r15 = lane & 15, kq = (lane >> 4) * 8;
    const float* qb = q + ((size_t)b * S_ + (size_t)qt * TILE) * D_;
    const float* kb = k + ((size_t)b * S_ + (size_t)kt * TILE) * D_;
    f32x4 acc[4][4] = {};
    for (int kk = 0; kk < D_; kk += BK) {
        __syncthreads();
        stage_granule(lA, qb + kk, D_, tid);
        stage_granule(lA, qb + kk, D_, tid + 256);
        stage_granule(lB, kb + kk, D_, tid);
        stage_granule(lB, kb + kk, D_, tid + 256);
        __syncthreads();
        s16x8 af[4], bf[4];
#pragma unroll
        for (int m = 0; m < 4; ++m) af[m] = load_frag(lA, wr + m * 16 + r15, kq);
#pragma unroll
        for (int n = 0; n < 4; ++n) bf[n] = load_frag(lB, wc + n * 16 + r15, kq);
#pragma unroll
        for (int m = 0; m < 4; ++m)
#pragma unroll
            for (int n = 0; n < 4; ++n)
                acc[m][n] = __builtin_amdgcn_mfma_f32_16x16x32_bf16(af[m], bf[n], acc[m][n], 0, 0, 0);
    }
    const float scale = 0.04419417382415922f;
    size_t base = ((size_t)b * S_ + (size_t)qt * TILE) * S_ + (size_t)kt * TILE;
    const int rr = (lane >> 4) * 4;
#pragma unroll
    for (int m = 0; m < 4; ++m)
#pragma unroll
        for (int n = 0; n < 4; ++n)
#pragma unroll
            for (int r = 0; r < 4; ++r)
                attn[base + (size_t)(wr + m * 16 + rr + r) * S_ + wc + n * 16 + r15] =
                    acc[m][n][r] * scale;
}

__global__ __launch_bounds__(256) void pv_kernel(const float* __restrict__ attn,
                                                 const float* __restrict__ v,
                                                 float* __restrict__ out) {
    const int dt = blockIdx.x, qt = blockIdx.y, b = blockIdx.z;
    __shared__ u16 lP[TILE * PITCH];
    __shared__ u16 lV[TILE * PITCH];
    const int tid = threadIdx.x;
    const int lane = tid & 63;
    const int wid = tid >> 6;
    const int wr = (wid >> 1) * 64, wc = (wid & 1) * 64;
    const int r15 = lane & 15, kq = (lane >> 4) * 8;
    const float* pb = attn + ((size_t)b * S_ + (size_t)qt * TILE) * S_;
    const float* vb = v + (size_t)b * S_ * D_ + (size_t)dt * TILE;
    const int vd0 = (tid & 31) * 4;
    const int vj0 = (tid >> 5) * 4;
    f32x4 acc[4][4] = {};
    const int nk = (qt + 1) * TILE;
    for (int kk = 0; kk < nk; kk += BK) {
        __syncthreads();
        stage_granule(lP, pb + kk, S_, tid);
        stage_granule(lP, pb + kk, S_, tid + 256);
        {
            const float* vs = vb + (size_t)(kk + vj0) * D_ + vd0;
            float4 r0 = *(const float4*)vs;
            float4 r1 = *(const float4*)(vs + D_);
            float4 r2 = *(const float4*)(vs + 2 * D_);
            float4 r3 = *(const float4*)(vs + 3 * D_);
            *(ushort4*)(lV + (vd0 + 0) * PITCH + vj0) = make_ushort4(f2bf(r0.x), f2bf(r1.x), f2bf(r2.x), f2bf(r3.x));
            *(ushort4*)(lV + (vd0 + 1) * PITCH + vj0) = make_ushort4(f2bf(r0.y), f2bf(r1.y), f2bf(r2.y), f2bf(r3.y));
            *(ushort4*)(lV + (vd0 + 2) * PITCH + vj0) = make_ushort4(f2bf(r0.z), f2bf(r1.z), f2bf(r2.z), f2bf(r3.z));
            *(ushort4*)(lV + (vd0 + 3) * PITCH + vj0) = make_ushort4(f2bf(r0.w), f2bf(r1.w), f2bf(r2.w), f2bf(r3.w));
        }
        __syncthreads();
        s16x8 af[4], bf[4];
#pragma unroll
        for (int m = 0; m < 4; ++m) af[m] = load_frag(lP, wr + m * 16 + r15, kq);
#pragma unroll
        for (int n = 0; n < 4; ++n) bf[n] = load_frag(lV, wc + n * 16 + r15, kq);
#pragma unroll
        for (int m = 0; m < 4; ++m)
#pragma unroll
            for (int n = 0; n < 4; ++n)
                acc[m][n] = __builtin_amdgcn_mfma_f32_16x16x32_bf16(af[m], bf[n], acc[m][n], 0, 0, 0);
    }
    size_t base = ((size_t)b * S_ + (size_t)qt * TILE) * D_ + (size_t)dt * TILE;
    const int rr = (lane >> 4) * 4;
#pragma unroll
    for (int m = 0; m < 4; ++m)
#pragma unroll
        for (int n = 0; n < 4; ++n)
#pragma unroll
            for (int r = 0; r < 4; ++r)
                out[base + (size_t)(wr + m * 16 + rr + r) * D_ + wc + n * 16 + r15] =
                    acc[m][n][r];
}

extern "C" void kernel_launch(void* const* d_in, const int* in_sizes, int n_in,
                              void* d_out, int out_size, void* d_ws, size_t ws_size,
                              hipStream_t stream) {
    const float* q = (const float*)d_in[0];
    const float* k = (const float*)d_in[1];
    const float* v = (const float*)d_in[2];
    const int* rep = (const int*)d_in[3];
    float* out = (float*)d_out;
    float* attn = out + (size_t)B_ * S_ * D_;   // second output region [B,S,S]

    const size_t nqk = (size_t)B_ * S_ * D_;        // 8.4M
    const size_t npt = (size_t)B_ * PT_BATCH;       // 9.4M
    const size_t nst = (size_t)B_ * 8 * S_;         // stats float2
    const size_t need_new = 3 * nqk * sizeof(u16) + npt * sizeof(u16) + nst * sizeof(float2); // 70.3 MB
    const size_t need_r8 = 3 * nqk * sizeof(u16);   // 50.3 MB

    if (ws_size >= need_new) {
        u16* Qb = (u16*)d_ws;
        u16* Kb = Qb + nqk;
        u16* Vt = Kb + nqk;
        u16* Pt = Vt + nqk;
        float2* st = (float2*)(Pt + npt);
        prep_kernel<<<10240, 256, 0, stream>>>(q, k, v, Qb, Kb, Vt);
        qk4_kernel<<<8 * 72, 256, 0, stream>>>(Qb, Kb, rep, Pt, st);
        pvsm3_kernel<<<8 * 64, 256, 0, stream>>>(Pt, st, rep, Vt, attn, out);
    } else if (ws_size >= need_r8) {
        u16* Qb = (u16*)d_ws;
        u16* Kb = Qb + nqk;
        u16* Vt = Kb + nqk;
        u16* Pb = (u16*)d_ws;   // aliases Qb+Kb; dead after qk2
        prep_kernel<<<10240, 256, 0, stream>>>(q, k, v, Qb, Kb, Vt);
        qk2_kernel<<<8 * 72, 256, 0, stream>>>(Qb, Kb, rep, attn);
        sm_kernel<<<dim3(S_, B_), 256, 0, stream>>>(rep, attn, Pb);
        pv2_kernel<<<8 * 64, 256, 0, stream>>>(Pb, Vt, out);
    } else {
        qk_kernel<<<dim3(S_ / TILE, S_ / TILE, B_), 256, 0, stream>>>(q, k, attn);
        sm_kernel<<<dim3(S_, B_), 256, 0, stream>>>(rep, attn, nullptr);
        pv_kernel<<<dim3(D_ / TILE, S_ / TILE, B_), 256, 0, stream>>>(attn, v, out);
    }
}

// Round 13
// 90.118 us; speedup vs baseline: 1.4423x; 1.1784x over previous
//
#include <hip/hip_runtime.h>
#include <cstdint>

#define B_ 16
#define S_ 1024
#define D_ 512
#define TILE 128
#define BK 32
#define PITCH 36   // legacy-path LDS pitch

typedef float f32x4 __attribute__((ext_vector_type(4)));
typedef short s16x8 __attribute__((ext_vector_type(8)));
typedef unsigned short u16;
typedef unsigned int u32;

__device__ __forceinline__ u16 f2bf(float f) {
    u32 u = __builtin_bit_cast(u32, f);
    u += 0x7FFFu + ((u >> 16) & 1u);
    return (u16)(u >> 16);
}

#define GLD16(g, l) __builtin_amdgcn_global_load_lds( \
    (const __attribute__((address_space(1))) u32*)(g), \
    (__attribute__((address_space(3))) u32*)(l), 16, 0, 0)

// ===== prep: cvt(Q) + cvt(K) + transpose-cvt(V) in one launch (proven) =====
#define TP 66
__global__ __launch_bounds__(256) void prep_kernel(const float* __restrict__ q,
                                                   const float* __restrict__ k,
                                                   const float* __restrict__ v,
                                                   u16* __restrict__ Qb,
                                                   u16* __restrict__ Kb,
                                                   u16* __restrict__ Vt) {
    __shared__ u16 t[64 * TP];
    const int bid = blockIdx.x;
    const int tid = threadIdx.x;
    if (bid < 8192) {   // cvt Q (bid<4096) or K
        const float* src = (bid < 4096) ? q : k;
        u16* dst = (bid < 4096) ? Qb : Kb;
        int i = (((bid & 4095) * 256) + tid) * 8;
        float4 a = *(const float4*)(src + i);
        float4 b2 = *(const float4*)(src + i + 4);
        union { ushort4 h[2]; s16x8 v; } r;
        r.h[0] = make_ushort4(f2bf(a.x), f2bf(a.y), f2bf(a.z), f2bf(a.w));
        r.h[1] = make_ushort4(f2bf(b2.x), f2bf(b2.y), f2bf(b2.z), f2bf(b2.w));
        *(s16x8*)(dst + i) = r.v;
    } else {            // trv tile
        int tt = bid - 8192;                 // 0..2047
        const int d0 = (tt & 7) * 64, j0 = ((tt >> 3) & 15) * 64, b = tt >> 7;
        const int tj = tid >> 2;
        const int td = (tid & 3) * 16;
        const float* src = v + ((size_t)b * S_ + j0 + tj) * D_ + d0 + td;
#pragma unroll
        for (int e = 0; e < 4; ++e) {
            float4 a = *(const float4*)(src + e * 4);
            *(ushort4*)(t + tj * TP + td + e * 4) =
                make_ushort4(f2bf(a.x), f2bf(a.y), f2bf(a.z), f2bf(a.w));
        }
        __syncthreads();
        const int dd = tid >> 2;
        const int jj = (tid & 3) * 16;
        u16* dstp = Vt + ((size_t)b * D_ + d0 + dd) * S_ + j0 + jj;
        u16 tmp[16];
#pragma unroll
        for (int e = 0; e < 16; ++e) tmp[e] = t[(jj + e) * TP + dd];
        *(s16x8*)dstp = *(s16x8*)tmp;
        *(s16x8*)(dstp + 8) = *(s16x8*)(tmp + 8);
    }
}

// swizzled LDS read: logical [row][col(64 bf16)] stored with byte ^= (row&7)<<4
__device__ __forceinline__ s16x8 frag_swz(const u16* lds, int row, int colbyte) {
    int off = row * 128 + (colbyte ^ ((row & 7) << 4));
    return *(const s16x8*)((const char*)lds + off);
}

// m97-style bf16 GEMM tile body (proven): 128x128, BK=64, global_load_lds + swizzle
__device__ __forceinline__ void gemm_body(const u16* ag, const u16* bg, int lda, int ldb,
                                          int nk, u16* lA, u16* lB, f32x4 acc[4][4],
                                          int tid) {
    const int lane = tid & 63, wid = tid >> 6;
    const int l8 = lane >> 3, l7 = lane & 7;
    const int cswz = (l7 ^ l8) * 8;
    const u16* ga[4];
    const u16* gb[4];
#pragma unroll
    for (int q2 = 0; q2 < 4; ++q2) {
        int seg = wid * 4 + q2;
        int row = seg * 8 + l8;
        ga[q2] = ag + (size_t)row * lda + cswz;
        gb[q2] = bg + (size_t)row * ldb + cswz;
    }
    const int wr = (wid >> 1) * 64, wc = (wid & 1) * 64;
    const int r15 = lane & 15;
    const int cb = (lane >> 4) * 16;

    for (int kk = 0; kk < nk; kk += 64) {
#pragma unroll
        for (int q2 = 0; q2 < 4; ++q2) {
            int seg = wid * 4 + q2;
            GLD16(ga[q2] + kk, lA + seg * 512);
            GLD16(gb[q2] + kk, lB + seg * 512);
        }
        __syncthreads();
#pragma unroll
        for (int ks = 0; ks < 2; ++ks) {
            s16x8 af[4], bf4[4];
#pragma unroll
            for (int m = 0; m < 4; ++m) af[m] = frag_swz(lA, wr + m * 16 + r15, ks * 64 + cb);
#pragma unroll
            for (int n = 0; n < 4; ++n) bf4[n] = frag_swz(lB, wc + n * 16 + r15, ks * 64 + cb);
#pragma unroll
            for (int m = 0; m < 4; ++m)
#pragma unroll
                for (int n = 0; n < 4; ++n)
                    acc[m][n] = __builtin_amdgcn_mfma_f32_16x16x32_bf16(af[m], bf4[n], acc[m][n], 0, 0, 0);
        }
        __syncthreads();
    }
}

// QK^T: 1D grid, XCD-chunked, LPT (heavy pairs first); skips stores for masked rows.
__global__ __launch_bounds__(256) void qk2_kernel(const u16* __restrict__ Qb,
                                                  const u16* __restrict__ Kb,
                                                  const int* __restrict__ rep,
                                                  float* __restrict__ attn) {
    const int bid = blockIdx.x;
    const int xcd = bid & 7;
    const int w = bid >> 3;            // 0..71
    const int b = xcd * 2 + (w & 1);
    int p = 35 - (w >> 1);             // LPT: large qt first
    int qt = 0, tri = 0;
    while (p >= tri + qt + 1) { tri += qt + 1; ++qt; }
    const int kt = p - tri;

    __shared__ u16 lA[128 * 64];
    __shared__ u16 lB[128 * 64];
    __shared__ int lrepr[128];
    const int tid = threadIdx.x, lane = tid & 63, wid = tid >> 6;
    if (tid < 128) lrepr[tid] = rep[(size_t)b * S_ + qt * 128 + tid];

    f32x4 acc[4][4] = {};
    gemm_body(Qb + ((size_t)b * S_ + (size_t)qt * 128) * D_,
              Kb + ((size_t)b * S_ + (size_t)kt * 128) * D_,
              D_, D_, D_, lA, lB, acc, tid);
    const float scale = 0.04419417382415922f;  // 1/sqrt(512)
    const int wr = (wid >> 1) * 64, wc = (wid & 1) * 64;
    const int r15 = lane & 15, rr = (lane >> 4) * 4;
    size_t base = ((size_t)b * S_ + (size_t)qt * 128) * S_ + (size_t)kt * 128;
#pragma unroll
    for (int m = 0; m < 4; ++m)
#pragma unroll
        for (int r = 0; r < 4; ++r) {
            const int row = wr + m * 16 + rr + r;
            if (lrepr[row]) {   // sm never reads rows with rep==0
#pragma unroll
                for (int n = 0; n < 4; ++n)
                    attn[base + (size_t)row * S_ + wc + n * 16 + r15] =
                        acc[m][n][r] * scale;
            }
        }
}

// PV from bf16 Pb (proven structure), LPT qt-descending
__global__ __launch_bounds__(256) void pv2_kernel(const u16* __restrict__ Pb,
                                                  const u16* __restrict__ Vt,
                                                  float* __restrict__ out) {
    const int bid = blockIdx.x;
    const int xcd = bid & 7;
    const int w = bid >> 3;
    const int b = xcd * 2 + (w & 1);
    const int r = w >> 1;
    const int dt = r & 3, qt = 7 - (r >> 2);   // heavy qt first

    __shared__ u16 lA[128 * 64];
    __shared__ u16 lB[128 * 64];
    const int tid = threadIdx.x, lane = tid & 63, wid = tid >> 6;
    f32x4 acc[4][4] = {};
    gemm_body(Pb + ((size_t)b * S_ + (size_t)qt * 128) * S_,
              Vt + ((size_t)b * D_ + (size_t)dt * 128) * S_,
              S_, S_, (qt + 1) * 128, lA, lB, acc, tid);
    const int wr = (wid >> 1) * 64, wc = (wid & 1) * 64;
    const int r15 = lane & 15, rr = (lane >> 4) * 4;
    size_t base = ((size_t)b * S_ + (size_t)qt * 128) * D_ + (size_t)dt * 128;
#pragma unroll
    for (int m = 0; m < 4; ++m)
#pragma unroll
        for (int n = 0; n < 4; ++n)
#pragma unroll
            for (int rg = 0; rg < 4; ++rg)
                out[base + (size_t)(wr + m * 16 + rr + rg) * D_ + wc + n * 16 + r15] =
                    acc[m][n][rg];
}

// ------------- masked softmax per row (in-place; bf16 P to ws) — proven -------------
__global__ __launch_bounds__(256) void sm_kernel(const int* __restrict__ rep_mask,
                                                 float* __restrict__ attn,
                                                 u16* __restrict__ pb) {
    const int i = blockIdx.x, b = blockIdx.y;
    const int tid = threadIdx.x;
    const int lane = tid & 63, wid = tid >> 6;
    float* row = attn + ((size_t)b * S_ + i) * S_;
    const int* rm = rep_mask + (size_t)b * S_;
    __shared__ float red[8];

    const int mi = rm[i];
    const int j0 = tid * 4;
    int4 m4 = ((const int4*)rm)[tid];
    float4 lv = make_float4(0.f, 0.f, 0.f, 0.f);
    if (mi != 0 && j0 < i) lv = *(const float4*)(row + j0);

    const int mv[4] = {m4.x, m4.y, m4.z, m4.w};
    const float lf[4] = {lv.x, lv.y, lv.z, lv.w};
    float vec[4];
    bool val[4];
    float mymax = 0.0f;  // masked entries contribute 0 to the max (reference semantics)
#pragma unroll
    for (int e = 0; e < 4; ++e) {
        int j = j0 + e;
        val[e] = (mi != 0) && (j < i) && (mv[e] != 0);
        vec[e] = lf[e] - (float)(i - j);
        if (val[e]) mymax = fmaxf(mymax, vec[e]);
    }
#pragma unroll
    for (int off = 32; off > 0; off >>= 1) mymax = fmaxf(mymax, __shfl_down(mymax, off));
    if (lane == 0) red[wid] = mymax;
    __syncthreads();
    const float m = fmaxf(fmaxf(red[0], red[1]), fmaxf(red[2], red[3]));

    float ex[4];
    float mysum = 0.0f;
#pragma unroll
    for (int e = 0; e < 4; ++e) {
        ex[e] = val[e] ? expf(vec[e] - m) : 0.0f;
        mysum += ex[e];
    }
#pragma unroll
    for (int off = 32; off > 0; off >>= 1) mysum += __shfl_down(mysum, off);
    if (lane == 0) red[4 + wid] = mysum;
    __syncthreads();
    const float ssum = red[4] + red[5] + red[6] + red[7];
    const float denom = ssum + (ssum == 0.0f ? 1.0f : 0.0f) + 1e-20f;
    const float inv = 1.0f / denom;
    float4 o = make_float4(ex[0] * inv, ex[1] * inv, ex[2] * inv, ex[3] * inv);
    *(float4*)(row + j0) = o;   // every position written -> no poison leaks
    if (pb != nullptr && j0 <= (i | 127)) {  // bf16 copy for PV, causal tiles only
        u16* pr = pb + ((size_t)b * S_ + i) * S_ + j0;
        *(ushort4*)pr = make_ushort4(f2bf(o.x), f2bf(o.y), f2bf(o.z), f2bf(o.w));
    }
}

// ======================= legacy fallback path (no ws) =======================

union Frag { s16x8 v; uint2 u[2]; };

__device__ __forceinline__ s16x8 load_frag(const u16* lds, int row, int kq) {
    Frag f;
    const u16* p = lds + row * PITCH + kq;
    f.u[0] = *(const uint2*)p;
    f.u[1] = *(const uint2*)(p + 4);
    return f.v;
}

__device__ __forceinline__ void stage_granule(u16* lds, const float* src, int ldsrc, int g) {
    int row = g >> 2;
    int c8 = (g & 3) * 8;
    const float4* s = (const float4*)(src + (size_t)row * ldsrc + c8);
    float4 x0 = s[0], x1 = s[1];
    *(ushort4*)(lds + row * PITCH + c8) =
        make_ushort4(f2bf(x0.x), f2bf(x0.y), f2bf(x0.z), f2bf(x0.w));
    *(ushort4*)(lds + row * PITCH + c8 + 4) =
        make_ushort4(f2bf(x1.x), f2bf(x1.y), f2bf(x1.z), f2bf(x1.w));
}

__global__ __launch_bounds__(256) void qk_kernel(const float* __restrict__ q,
                                                 const float* __restrict__ k,
                                                 float* __restrict__ attn) {
    const int kt = blockIdx.x, qt = blockIdx.y, b = blockIdx.z;
    if (kt > qt) return;
    __shared__ u16 lA[TILE * PITCH];
    __shared__ u16 lB[TILE * PITCH];
    const int tid = threadIdx.x;
    const int lane = tid & 63;
    const int wid = tid >> 6;
    const int wr = (wid >> 1) * 64, wc = (wid & 1) * 64;
    const int r15 = lane & 15, kq = (lane >> 4) * 8;
    const float* qb = q + ((size_t)b * S_ + (size_t)qt * TILE) * D_;
    const float* kb = k + ((size_t)b * S_ + (size_t)kt * TILE) * D_;
    f32x4 acc[4][4] = {};
    for (int kk = 0; kk < D_; kk += BK) {
        __syncthreads();
        stage_granule(lA, qb + kk, D_, tid);
        stage_granule(lA, qb + kk, D_, tid + 256);
        stage_granule(lB, kb + kk, D_, tid);
        stage_granule(lB, kb + kk, D_, tid + 256);
        __syncthreads();
        s16x8 af[4], bf[4];
#pragma unroll
        for (int m = 0; m < 4; ++m) af[m] = load_frag(lA, wr + m * 16 + r15, kq);
#pragma unroll
        for (int n = 0; n < 4; ++n) bf[n] = load_frag(lB, wc + n * 16 + r15, kq);
#pragma unroll
        for (int m = 0; m < 4; ++m)
#pragma unroll
            for (int n = 0; n < 4; ++n)
                acc[m][n] = __builtin_amdgcn_mfma_f32_16x16x32_bf16(af[m], bf[n], acc[m][n], 0, 0, 0);
    }
    const float scale = 0.04419417382415922f;
    size_t base = ((size_t)b * S_ + (size_t)qt * TILE) * S_ + (size_t)kt * TILE;
    const int rr = (lane >> 4) * 4;
#pragma unroll
    for (int m = 0; m < 4; ++m)
#pragma unroll
        for (int n = 0; n < 4; ++n)
#pragma unroll
            for (int r = 0; r < 4; ++r)
                attn[base + (size_t)(wr + m * 16 + rr + r) * S_ + wc + n * 16 + r15] =
                    acc[m][n][r] * scale;
}

__global__ __launch_bounds__(256) void pv_kernel(const float* __restrict__ attn,
                                                 const float* __restrict__ v,
                                                 float* __restrict__ out) {
    const int dt = blockIdx.x, qt = blockIdx.y, b = blockIdx.z;
    __shared__ u16 lP[TILE * PITCH];
    __shared__ u16 lV[TILE * PITCH];
    const int tid = threadIdx.x;
    const int lane = tid & 63;
    const int wid = tid >> 6;
    const int wr = (wid >> 1) * 64, wc = (wid & 1) * 64;
    const int r15 = lane & 15, kq = (lane >> 4) * 8;
    const float* pb = attn + ((size_t)b * S_ + (size_t)qt * TILE) * S_;
    const float* vb = v + (size_t)b * S_ * D_ + (size_t)dt * TILE;
    const int vd0 = (tid & 31) * 4;
    const int vj0 = (tid >> 5) * 4;
    f32x4 acc[4][4] = {};
    const int nk = (qt + 1) * TILE;
    for (int kk = 0; kk < nk; kk += BK) {
        __syncthreads();
        stage_granule(lP, pb + kk, S_, tid);
        stage_granule(lP, pb + kk, S_, tid + 256);
        {
            const float* vs = vb + (size_t)(kk + vj0) * D_ + vd0;
            float4 r0 = *(const float4*)vs;
            float4 r1 = *(const float4*)(vs + D_);
            float4 r2 = *(const float4*)(vs + 2 * D_);
            float4 r3 = *(const float4*)(vs + 3 * D_);
            *(ushort4*)(lV + (vd0 + 0) * PITCH + vj0) = make_ushort4(f2bf(r0.x), f2bf(r1.x), f2bf(r2.x), f2bf(r3.x));
            *(ushort4*)(lV + (vd0 + 1) * PITCH + vj0) = make_ushort4(f2bf(r0.y), f2bf(r1.y), f2bf(r2.y), f2bf(r3.y));
            *(ushort4*)(lV + (vd0 + 2) * PITCH + vj0) = make_ushort4(f2bf(r0.z), f2bf(r1.z), f2bf(r2.z), f2bf(r3.z));
            *(ushort4*)(lV + (vd0 + 3) * PITCH + vj0) = make_ushort4(f2bf(r0.w), f2bf(r1.w), f2bf(r2.w), f2bf(r3.w));
        }
        __syncthreads();
        s16x8 af[4], bf[4];
#pragma unroll
        for (int m = 0; m < 4; ++m) af[m] = load_frag(lP, wr + m * 16 + r15, kq);
#pragma unroll
        for (int n = 0; n < 4; ++n) bf[n] = load_frag(lV, wc + n * 16 + r15, kq);
#pragma unroll
        for (int m = 0; m < 4; ++m)
#pragma unroll
            for (int n = 0; n < 4; ++n)
                acc[m][n] = __builtin_amdgcn_mfma_f32_16x16x32_bf16(af[m], bf[n], acc[m][n], 0, 0, 0);
    }
    size_t base = ((size_t)b * S_ + (size_t)qt * TILE) * D_ + (size_t)dt * TILE;
    const int rr = (lane >> 4) * 4;
#pragma unroll
    for (int m = 0; m < 4; ++m)
#pragma unroll
        for (int n = 0; n < 4; ++n)
#pragma unroll
            for (int r = 0; r < 4; ++r)
                out[base + (size_t)(wr + m * 16 + rr + r) * D_ + wc + n * 16 + r15] =
                    acc[m][n][r];
}

extern "C" void kernel_launch(void* const* d_in, const int* in_sizes, int n_in,
                              void* d_out, int out_size, void* d_ws, size_t ws_size,
                              hipStream_t stream) {
    const float* q = (const float*)d_in[0];
    const float* k = (const float*)d_in[1];
    const float* v = (const float*)d_in[2];
    const int* rep = (const int*)d_in[3];
    float* out = (float*)d_out;
    float* attn = out + (size_t)B_ * S_ * D_;   // second output region [B,S,S]

    const size_t nqk = (size_t)B_ * S_ * D_;           // 8.4M elems per tensor
    const size_t need = 3 * nqk * sizeof(u16);         // Qb + Kb + Vt = 50.3 MB
    if (ws_size >= need) {
        u16* Qb = (u16*)d_ws;
        u16* Kb = Qb + nqk;
        u16* Vt = Kb + nqk;
        u16* Pb = (u16*)d_ws;   // aliases Qb+Kb (exactly B*S*S bf16); dead after qk2
        prep_kernel<<<10240, 256, 0, stream>>>(q, k, v, Qb, Kb, Vt);
        qk2_kernel<<<8 * 72, 256, 0, stream>>>(Qb, Kb, rep, attn);
        sm_kernel<<<dim3(S_, B_), 256, 0, stream>>>(rep, attn, Pb);
        pv2_kernel<<<8 * 64, 256, 0, stream>>>(Pb, Vt, out);
    } else {
        qk_kernel<<<dim3(S_ / TILE, S_ / TILE, B_), 256, 0, stream>>>(q, k, attn);
        sm_kernel<<<dim3(S_, B_), 256, 0, stream>>>(rep, attn, nullptr);
        pv_kernel<<<dim3(D_ / TILE, S_ / TILE, B_), 256, 0, stream>>>(attn, v, out);
    }
}